// Round 7
// baseline (526.730 us; speedup 1.0000x reference)
//
#include <hip/hip_runtime.h>
#include <math.h>

typedef __attribute__((ext_vector_type(8))) short short8;
typedef __attribute__((ext_vector_type(4))) float floatx4;

#define HDIM 128
#define NPB 256          // nodes per bucket (CSR build)
#define BKMAX 1024       // max buckets (N <= 262144)
#define CHUNK 8192       // edges per pair_scatter block
#define STAGE_CAP 8192   // per-bucket srclist LDS stage (ints)

__device__ __forceinline__ float bf2f(unsigned short u) {
    unsigned int x = ((unsigned int)u) << 16;
    float f;
    __builtin_memcpy(&f, &x, 4);
    return f;
}
__device__ __forceinline__ unsigned short f2bf(float f) {
    unsigned int x;
    __builtin_memcpy(&x, &f, 4);
    unsigned int r = (x + 0x7fffu + ((x >> 16) & 1u)) >> 16;  // RNE
    return (unsigned short)r;
}
// split: hi = truncated bf16 (cheap), lo = RNE bf16 of residual.
// |lo| <= 2^-8|v|, residual-of-residual <= 2^-17|v| -- same quality as RNE hi.
__device__ __forceinline__ void split1(float v, unsigned short& hi, unsigned short& lo) {
    unsigned int x;
    __builtin_memcpy(&x, &v, 4);
    hi = (unsigned short)(x >> 16);
    lo = f2bf(v - bf2f(hi));
}
__device__ __forceinline__ float fast_sigmoid(float x) {
    return 1.0f / (1.0f + __expf(-x));
}
__device__ __forceinline__ float fast_tanh(float x) {
    // NaN-safe: compute on |x|, restore sign. Large |x| -> e=inf -> t=1.
    float ax = fabsf(x);
    float e = __expf(2.0f * ax);
    float t = 1.0f - 2.0f / (e + 1.0f);
    return copysignf(t, x);
}

// 16B async global->LDS (direct-to-shared DMA; dest is wave-uniform base + lane*16)
__device__ __forceinline__ void gload_lds16(const void* g, void* lds) {
    __builtin_amdgcn_global_load_lds(
        (const __attribute__((address_space(1))) unsigned int*)g,
        (__attribute__((address_space(3))) unsigned int*)lds, 16, 0, 0);
}

// ---------- split fp32 tensor into bf16 hi/lo planes (z) ----------
__global__ void split_plane_kernel(const float* __restrict__ src,
                                   unsigned short* __restrict__ hi,
                                   unsigned short* __restrict__ lo, long n) {
    long i = (long)blockIdx.x * 256 + threadIdx.x;
    if (i < n) {
        unsigned short h, l;
        split1(src[i], h, l);
        hi[i] = h; lo[i] = l;
    }
}

// ---------- fused weight prep: Wih split, W1/W2 transpose-split, W3 split, bias sum ----------
// index ranges: [0,65536) Wih | [65536,81920) W1^T | [81920,98304) W2^T |
//               [98304,114688) W3 | [114688,115200) bsum
__global__ void prep_weights_kernel(const float* __restrict__ Wih,
                                    const float* __restrict__ W1,
                                    const float* __restrict__ W2,
                                    const float* __restrict__ W3,
                                    const float* __restrict__ bih,
                                    const float* __restrict__ bhh,
                                    unsigned short* __restrict__ Wihh, unsigned short* __restrict__ Wihl,
                                    unsigned short* __restrict__ W1h,  unsigned short* __restrict__ W1l,
                                    unsigned short* __restrict__ W2h,  unsigned short* __restrict__ W2l,
                                    unsigned short* __restrict__ W3h,  unsigned short* __restrict__ W3l,
                                    float* __restrict__ bsum) {
    int i = blockIdx.x * 256 + threadIdx.x;
    unsigned short h, l;
    if (i < 65536) {
        split1(Wih[i], h, l);
        Wihh[i] = h; Wihl[i] = l;
    } else if (i < 81920) {
        int t = i - 65536, r = t >> 7, c = t & 127;
        split1(W1[r * HDIM + c], h, l);
        W1h[c * HDIM + r] = h; W1l[c * HDIM + r] = l;
    } else if (i < 98304) {
        int t = i - 81920, r = t >> 7, c = t & 127;
        split1(W2[r * HDIM + c], h, l);
        W2h[c * HDIM + r] = h; W2l[c * HDIM + r] = l;
    } else if (i < 114688) {
        int t = i - 98304;
        split1(W3[t], h, l);
        W3h[t] = h; W3l[t] = l;
    } else if (i < 115200) {
        int t = i - 114688;
        bsum[t] = bih[t] + bhh[t];
    }
}

// ================= bucketed CSR build =================
__global__ __launch_bounds__(256)
void bucket_hist_kernel(const int* __restrict__ ei, int* __restrict__ bcnt,
                        long E, int K) {
    __shared__ int h[BKMAX];
    const int tid = threadIdx.x;
    for (int i = tid; i < K; i += 256) h[i] = 0;
    __syncthreads();
    const long base = (long)blockIdx.x * CHUNK;
#pragma unroll
    for (int j = 0; j < CHUNK / 256; ++j) {
        long e = base + j * 256 + tid;
        if (e < E) atomicAdd(&h[((unsigned)ei[E + e]) >> 8], 1);
    }
    __syncthreads();
    for (int i = tid; i < K; i += 256) {
        int c = h[i];
        if (c) atomicAdd(&bcnt[i], c);
    }
}

__global__ __launch_bounds__(1024)
void scan_buckets_kernel(const int* __restrict__ bcnt, int* __restrict__ gbase,
                         int* __restrict__ gcur, int* __restrict__ offs,
                         int K, int N, int Etot) {
    __shared__ int buf[1024];
    const int t = threadIdx.x;
    const int v = (t < K) ? bcnt[t] : 0;
    buf[t] = v;
    __syncthreads();
    for (int off = 1; off < 1024; off <<= 1) {
        int x = buf[t];
        int y = (t >= off) ? buf[t - off] : 0;
        __syncthreads();
        buf[t] = x + y;
        __syncthreads();
    }
    if (t < K) { gbase[t] = buf[t] - v; gcur[t] = buf[t] - v; }
    if (t == 0) { gbase[K] = Etot; offs[N] = Etot; }
}

__global__ __launch_bounds__(256)
void pair_scatter_kernel(const int* __restrict__ ei, int* __restrict__ gcur,
                         unsigned int* __restrict__ pairs, long E, int K) {
    __shared__ int h[BKMAX];
    __shared__ int cur[BKMAX];
    const int tid = threadIdx.x;
    for (int i = tid; i < K; i += 256) h[i] = 0;
    __syncthreads();
    const long base = (long)blockIdx.x * CHUNK;
#pragma unroll
    for (int j = 0; j < CHUNK / 256; ++j) {
        long e = base + j * 256 + tid;
        if (e < E) atomicAdd(&h[((unsigned)ei[E + e]) >> 8], 1);
    }
    __syncthreads();
    for (int i = tid; i < K; i += 256) {
        int c = h[i];
        cur[i] = c ? atomicAdd(&gcur[i], c) : 0;
    }
    __syncthreads();
#pragma unroll
    for (int j = 0; j < CHUNK / 256; ++j) {
        long e = base + j * 256 + tid;
        if (e < E) {
            unsigned int s = (unsigned int)ei[e];
            unsigned int d = (unsigned int)ei[E + e];
            int b = d >> 8;
            int pos = atomicAdd(&cur[b], 1);
            pairs[pos] = s | ((d & (NPB - 1)) << 24);
        }
    }
}

__global__ __launch_bounds__(256)
void bucket_csr_kernel(const unsigned int* __restrict__ pairs, const int* __restrict__ gbase,
                       int* __restrict__ offs, float* __restrict__ dinv,
                       int* __restrict__ srclist, int N) {
    __shared__ int cnt[NPB];
    __shared__ int red[NPB];
    __shared__ int cur[NPB];
    __shared__ int stage[STAGE_CAP];
    const int tid = threadIdx.x;
    const int b = blockIdx.x;
    const int node0 = b << 8;
    const int nn = min(NPB, N - node0);
    const int ebeg = gbase[b];
    const int eend = gbase[b + 1];
    const int ne = eend - ebeg;

    cnt[tid] = 0;
    __syncthreads();
    for (int i = tid; i < ne; i += 256)
        atomicAdd(&cnt[pairs[ebeg + i] >> 24], 1);
    __syncthreads();
    const int myc = cnt[tid];
    red[tid] = myc;
    __syncthreads();
    for (int off = 1; off < NPB; off <<= 1) {
        int x = red[tid];
        int y = (tid >= off) ? red[tid - off] : 0;
        __syncthreads();
        red[tid] = x + y;
        __syncthreads();
    }
    const int loff = red[tid] - myc;   // exclusive
    if (tid < nn) {
        offs[node0 + tid] = ebeg + loff;
        dinv[node0 + tid] = rsqrtf((float)myc + 1.0f);   // +1 self-loop
    }
    cur[tid] = loff;
    __syncthreads();

    if (ne <= STAGE_CAP) {
        for (int i = tid; i < ne; i += 256) {
            unsigned int p = pairs[ebeg + i];
            int pos = atomicAdd(&cur[p >> 24], 1);
            stage[pos] = (int)(p & 0xFFFFFFu);
        }
        __syncthreads();
        for (int i = tid; i < ne; i += 256)
            srclist[ebeg + i] = stage[i];
    } else {  // overflow fallback (never expected at this E/K)
        for (int i = tid; i < ne; i += 256) {
            unsigned int p = pairs[ebeg + i];
            int pos = atomicAdd(&cur[p >> 24], 1);
            srclist[ebeg + pos] = (int)(p & 0xFFFFFFu);
        }
    }
}

// ---------- swizzled LDS staging via global_load_lds (512-thread blocks) ----------
// Stage a [nrows x 64] short plane (global pitch 128 shorts) into LDS, pitch 64,
// 16B chunks XOR-swizzled: LDS slot (r, cS) holds global chunk (r, cS ^ (r&7)).
__device__ __forceinline__ void stage_swz(const unsigned short* __restrict__ g,
                                          long rowBase, long maxRow, int kOff,
                                          unsigned short* lds, int nrows, int tid) {
    const int nchunks = nrows << 3;        // 8 chunks (16B) per 64-col row
    for (int L = tid; L < nchunks; L += 512) {
        int r = L >> 3, cS = L & 7;
        int cG = cS ^ (r & 7);
        long gr = rowBase + r;
        if (gr >= maxRow) gr = maxRow - 1;
        gload_lds16(g + gr * HDIM + kOff + cG * 8, lds + (long)L * 8);
    }
}

// fragment read offset (in shorts) for row r, chunk c0 in a swizzled plane
__device__ __forceinline__ int swz_off(int r, int c0) {
    return (r * 8 + (c0 ^ (r & 7))) * 8;
}

// ---------- split-bf16 GEMM: C[m,n] = sum_k A[m,k]*B[n,k], M x 128, K=128 ----------
// 512 threads, 128-row M tile (8 waves x 16 rows).
// mode 0: outb = bf16( C * rowScale[m] )   (pre-scaled message for GCN)
// mode 1: outf = relu(C + bias[n])         (final layer, fp32)
__global__ __launch_bounds__(512, 4)
void gemm_split(const unsigned short* __restrict__ Ah, const unsigned short* __restrict__ Al,
                const unsigned short* __restrict__ Bh, const unsigned short* __restrict__ Bl,
                float* __restrict__ outf, unsigned short* __restrict__ outb, long M,
                const float* __restrict__ rowScale,
                const float* __restrict__ bias, int mode)
{
    __shared__ unsigned short sAh[128 * 64], sAl[128 * 64];
    __shared__ unsigned short sBh[128 * 64], sBl[128 * 64];
    const int tid = threadIdx.x;
    const long rowBase = (long)blockIdx.x * 128;

    const int wave = tid >> 6;      // 0..7
    const int lane = tid & 63;
    const int quad = lane >> 4;
    const int l16  = lane & 15;
    const int arow = wave * 16 + l16;

    floatx4 acc[8];
#pragma unroll
    for (int i = 0; i < 8; ++i) acc[i] = (floatx4)0.0f;

    for (int h = 0; h < 2; ++h) {
        __syncthreads();
        stage_swz(Ah, rowBase, M, h * 64, sAh, 128, tid);
        stage_swz(Al, rowBase, M, h * 64, sAl, 128, tid);
        stage_swz(Bh, 0, 128, h * 64, sBh, 128, tid);
        stage_swz(Bl, 0, 128, h * 64, sBl, 128, tid);
        __syncthreads();
#pragma unroll
        for (int kk = 0; kk < 2; ++kk) {
            const int c0 = kk * 4 + quad;
            const int ao = swz_off(arow, c0);
            short8 ah = *(const short8*)(sAh + ao);
            short8 al = *(const short8*)(sAl + ao);
#pragma unroll
            for (int ct = 0; ct < 8; ++ct) {
                const int bo = swz_off(ct * 16 + l16, c0);
                short8 bh = *(const short8*)(sBh + bo);
                short8 bl = *(const short8*)(sBl + bo);
                acc[ct] = __builtin_amdgcn_mfma_f32_16x16x32_bf16(ah, bh, acc[ct], 0, 0, 0);
                acc[ct] = __builtin_amdgcn_mfma_f32_16x16x32_bf16(ah, bl, acc[ct], 0, 0, 0);
                acc[ct] = __builtin_amdgcn_mfma_f32_16x16x32_bf16(al, bh, acc[ct], 0, 0, 0);
            }
        }
    }

#pragma unroll
    for (int ct = 0; ct < 8; ++ct) {
#pragma unroll
        for (int r = 0; r < 4; ++r) {
            long m = rowBase + wave * 16 + quad * 4 + r;
            if (m < M) {
                int n = ct * 16 + l16;
                float v = acc[ct][r];
                if (mode == 0) {
                    v *= rowScale[m];
                    outb[m * HDIM + n] = f2bf(v);
                } else {
                    v += bias[n];
                    v = fmaxf(v, 0.0f);
                    outf[m * HDIM + n] = v;
                }
            }
        }
    }
}

// ---------- LSTM: gates = z @ W_ih^T + bsum (f gate dead, h0=c0=0) ----------
// 512 threads, 128-row M tile.
__global__ __launch_bounds__(512, 2)
void lstm_gemm_split(const unsigned short* __restrict__ Zh, const unsigned short* __restrict__ Zl,
                     const unsigned short* __restrict__ Wh, const unsigned short* __restrict__ Wl,
                     const float* __restrict__ bsum,
                     unsigned short* __restrict__ Hh, unsigned short* __restrict__ Hl, long M)
{
    __shared__ unsigned short sAh[128 * 64], sAl[128 * 64];
    __shared__ unsigned short sBh[128 * 64], sBl[128 * 64];
    const int tid = threadIdx.x;
    const long rowBase = (long)blockIdx.x * 128;

    const int wave = tid >> 6;
    const int lane = tid & 63;
    const int quad = lane >> 4;
    const int l16  = lane & 15;
    const int arow = wave * 16 + l16;

    floatx4 acc[3][8];
#pragma unroll
    for (int g = 0; g < 3; ++g)
#pragma unroll
        for (int i = 0; i < 8; ++i) acc[g][i] = (floatx4)0.0f;

    const int gateRow[3] = {0, 256, 384};   // i, g, o
    for (int h = 0; h < 2; ++h) {
        for (int g = 0; g < 3; ++g) {
            __syncthreads();   // prior reads done before LDS overwrite
            if (g == 0) {
                stage_swz(Zh, rowBase, M, h * 64, sAh, 128, tid);
                stage_swz(Zl, rowBase, M, h * 64, sAl, 128, tid);
            }
            stage_swz(Wh + (long)gateRow[g] * HDIM, 0, 1 << 30, h * 64, sBh, 128, tid);
            stage_swz(Wl + (long)gateRow[g] * HDIM, 0, 1 << 30, h * 64, sBl, 128, tid);
            __syncthreads();
#pragma unroll
            for (int kk = 0; kk < 2; ++kk) {
                const int c0 = kk * 4 + quad;
                const int ao = swz_off(arow, c0);
                short8 ah = *(const short8*)(sAh + ao);
                short8 al = *(const short8*)(sAl + ao);
#pragma unroll
                for (int ct = 0; ct < 8; ++ct) {
                    const int bo = swz_off(ct * 16 + l16, c0);
                    short8 bh = *(const short8*)(sBh + bo);
                    short8 bl = *(const short8*)(sBl + bo);
                    acc[g][ct] = __builtin_amdgcn_mfma_f32_16x16x32_bf16(ah, bh, acc[g][ct], 0, 0, 0);
                    acc[g][ct] = __builtin_amdgcn_mfma_f32_16x16x32_bf16(ah, bl, acc[g][ct], 0, 0, 0);
                    acc[g][ct] = __builtin_amdgcn_mfma_f32_16x16x32_bf16(al, bh, acc[g][ct], 0, 0, 0);
                }
            }
        }
    }

#pragma unroll
    for (int ct = 0; ct < 8; ++ct) {
#pragma unroll
        for (int r = 0; r < 4; ++r) {
            long m = rowBase + wave * 16 + quad * 4 + r;
            if (m < M) {
                int n = ct * 16 + l16;
                float iv = acc[0][ct][r] + bsum[n];
                float gv = acc[1][ct][r] + bsum[256 + n];
                float ov = acc[2][ct][r] + bsum[384 + n];
                float cv = fast_sigmoid(iv) * fast_tanh(gv);
                float hv = fast_sigmoid(ov) * fast_tanh(cv);
                unsigned short hh, hl;
                split1(hv, hh, hl);
                Hh[m * HDIM + n] = hh;
                Hl[m * HDIM + n] = hl;
            }
        }
    }
}

// ---------- pull aggregation over bf16 messages ----------
__global__ __launch_bounds__(256, 4)
void aggregate_kernel(const unsigned short* __restrict__ t, const int* __restrict__ srclist,
                      const int* __restrict__ offs, const float* __restrict__ dinv,
                      const float* __restrict__ bias, int doRelu,
                      unsigned short* __restrict__ Xh, unsigned short* __restrict__ Xl, long N)
{
    long node = (long)blockIdx.x * 4 + (threadIdx.x >> 6);
    if (node >= N) return;
    const int lane = threadIdx.x & 63;
    const int c = lane * 2;
    const int beg = offs[node];
    const int end = offs[node + 1];
    float a0 = 0.0f, a1 = 0.0f, b0 = 0.0f, b1 = 0.0f;
    float c0 = 0.0f, c1 = 0.0f, d0 = 0.0f, d1 = 0.0f;
    int j = beg;
    for (; j + 4 <= end; j += 4) {
        const int s0 = srclist[j];
        const int s1 = srclist[j + 1];
        const int s2 = srclist[j + 2];
        const int s3 = srclist[j + 3];
        const unsigned int p0 = *(const unsigned int*)(t + (long)s0 * HDIM + c);
        const unsigned int p1 = *(const unsigned int*)(t + (long)s1 * HDIM + c);
        const unsigned int p2 = *(const unsigned int*)(t + (long)s2 * HDIM + c);
        const unsigned int p3 = *(const unsigned int*)(t + (long)s3 * HDIM + c);
        a0 += bf2f((unsigned short)(p0 & 0xffffu)); a1 += bf2f((unsigned short)(p0 >> 16));
        b0 += bf2f((unsigned short)(p1 & 0xffffu)); b1 += bf2f((unsigned short)(p1 >> 16));
        c0 += bf2f((unsigned short)(p2 & 0xffffu)); c1 += bf2f((unsigned short)(p2 >> 16));
        d0 += bf2f((unsigned short)(p3 & 0xffffu)); d1 += bf2f((unsigned short)(p3 >> 16));
    }
    for (; j < end; ++j) {
        const int s0 = srclist[j];
        const unsigned int p0 = *(const unsigned int*)(t + (long)s0 * HDIM + c);
        a0 += bf2f((unsigned short)(p0 & 0xffffu)); a1 += bf2f((unsigned short)(p0 >> 16));
    }
    const unsigned int ps = *(const unsigned int*)(t + node * HDIM + c);
    a0 += bf2f((unsigned short)(ps & 0xffffu));     // self-loop term
    a1 += bf2f((unsigned short)(ps >> 16));
    const float d = dinv[node];
    float v0 = d * (a0 + b0 + c0 + d0) + bias[c];
    float v1 = d * (a1 + b1 + c1 + d1) + bias[c + 1];
    if (doRelu) { v0 = fmaxf(v0, 0.0f); v1 = fmaxf(v1, 0.0f); }
    unsigned short h0, l0, h1, l1;
    split1(v0, h0, l0);
    split1(v1, h1, l1);
    *(unsigned int*)(Xh + node * HDIM + c) = (unsigned int)h0 | ((unsigned int)h1 << 16);
    *(unsigned int*)(Xl + node * HDIM + c) = (unsigned int)l0 | ((unsigned int)l1 << 16);
}

extern "C" void kernel_launch(void* const* d_in, const int* in_sizes, int n_in,
                              void* d_out, int out_size, void* d_ws, size_t ws_size,
                              hipStream_t stream)
{
    const float* z   = (const float*)d_in[0];
    const int*   ei  = (const int*)d_in[1];
    const float* Wih = (const float*)d_in[2];
    /* d_in[3] = W_hh: unused (h0 = 0) */
    const float* bih = (const float*)d_in[4];
    const float* bhh = (const float*)d_in[5];
    const float* W1  = (const float*)d_in[6];
    const float* b1  = (const float*)d_in[7];
    const float* W2  = (const float*)d_in[8];
    const float* b2  = (const float*)d_in[9];
    const float* W3  = (const float*)d_in[10];
    const float* b3  = (const float*)d_in[11];
    float* out = (float*)d_out;

    const long N = in_sizes[0] / HDIM;
    const long E = in_sizes[1] / 2;
    const int  K = (int)((N + NPB - 1) / NPB);   // buckets

    char* ws = (char*)d_ws;
    size_t off = 0;
    auto alloc = [&](size_t bytes) {
        char* p = ws + off;
        off += (bytes + 255) & ~(size_t)255;
        return (void*)p;
    };
    int*   bcnt    = (int*)alloc(K * 4);
    int*   gbase   = (int*)alloc((K + 1) * 4);
    int*   gcur    = (int*)alloc(K * 4);
    int*   offs    = (int*)alloc((N + 1) * 4);
    float* dinv    = (float*)alloc(N * 4);
    unsigned int* pairs = (unsigned int*)alloc(E * 4);
    int*   srclist = (int*)alloc(E * 4);
    unsigned short* P1h = (unsigned short*)alloc(N * HDIM * 2);  // z planes -> x1 planes
    unsigned short* P1l = (unsigned short*)alloc(N * HDIM * 2);
    unsigned short* P2h = (unsigned short*)alloc(N * HDIM * 2);  // h planes -> x2 planes
    unsigned short* P2l = (unsigned short*)alloc(N * HDIM * 2);
    unsigned short* Tb  = (unsigned short*)alloc(N * HDIM * 2);  // scaled messages (bf16)
    unsigned short* Wihh = (unsigned short*)alloc(512 * HDIM * 2);
    unsigned short* Wihl = (unsigned short*)alloc(512 * HDIM * 2);
    unsigned short* W1h  = (unsigned short*)alloc(HDIM * HDIM * 2);
    unsigned short* W1l  = (unsigned short*)alloc(HDIM * HDIM * 2);
    unsigned short* W2h  = (unsigned short*)alloc(HDIM * HDIM * 2);
    unsigned short* W2l  = (unsigned short*)alloc(HDIM * HDIM * 2);
    unsigned short* W3h  = (unsigned short*)alloc(HDIM * HDIM * 2);
    unsigned short* W3l  = (unsigned short*)alloc(HDIM * HDIM * 2);
    float* bsum = (float*)alloc(512 * 4);

    const int gblocks = (int)((N + 127) / 128);
    const int ablocks = (int)((N + 3) / 4);
    const int cblocks = (int)((E + CHUNK - 1) / CHUNK);

    // ---- bucketed CSR build (offs, srclist, dinv) ----
    hipMemsetAsync(bcnt, 0, K * 4, stream);
    bucket_hist_kernel<<<cblocks, 256, 0, stream>>>(ei, bcnt, E, K);
    scan_buckets_kernel<<<1, 1024, 0, stream>>>(bcnt, gbase, gcur, offs, K, (int)N, (int)E);
    pair_scatter_kernel<<<cblocks, 256, 0, stream>>>(ei, gcur, pairs, E, K);
    bucket_csr_kernel<<<K, 256, 0, stream>>>(pairs, gbase, offs, dinv, srclist, (int)N);

    // splits
    split_plane_kernel<<<(int)((N * HDIM + 255) / 256), 256, 0, stream>>>(z, P1h, P1l, N * HDIM);
    prep_weights_kernel<<<451, 256, 0, stream>>>(Wih, W1, W2, W3, bih, bhh,
                                                 Wihh, Wihl, W1h, W1l, W2h, W2l, W3h, W3l, bsum);

    // h = lstm(z)  -> P2 planes
    lstm_gemm_split<<<gblocks, 512, 0, stream>>>(P1h, P1l, Wihh, Wihl, bsum, P2h, P2l, N);

    // layer 1: Tb = bf16((h @ W1) * dinv) ; aggregate -> x1 planes (relu)
    gemm_split<<<gblocks, 512, 0, stream>>>(P2h, P2l, W1h, W1l, nullptr, Tb, N, dinv, nullptr, 0);
    aggregate_kernel<<<ablocks, 256, 0, stream>>>(Tb, srclist, offs, dinv, b1, 1, P1h, P1l, N);

    // layer 2: Tb = bf16((x1 @ W2) * dinv) ; aggregate -> x2 planes (no relu)
    gemm_split<<<gblocks, 512, 0, stream>>>(P1h, P1l, W2h, W2l, nullptr, Tb, N, dinv, nullptr, 0);
    aggregate_kernel<<<ablocks, 256, 0, stream>>>(Tb, srclist, offs, dinv, b2, 0, P2h, P2l, N);

    // out = relu(x2 @ W3^T + b3)
    gemm_split<<<gblocks, 512, 0, stream>>>(P2h, P2l, W3h, W3l, out, nullptr, N, nullptr, b3, 1);
}

// Round 8
// 463.844 us; speedup vs baseline: 1.1356x; 1.1356x over previous
//
#include <hip/hip_runtime.h>
#include <math.h>

typedef __attribute__((ext_vector_type(8))) short short8;
typedef __attribute__((ext_vector_type(4))) float floatx4;

#define HDIM 128
#define NPB 256          // nodes per bucket (CSR build)
#define BKMAX 1024       // max buckets (N <= 262144)
#define CHUNK 8192       // edges per pair_scatter block
#define STAGE_CAP 8192   // per-bucket srclist LDS stage (ints)

__device__ __forceinline__ float bf2f(unsigned short u) {
    unsigned int x = ((unsigned int)u) << 16;
    float f;
    __builtin_memcpy(&f, &x, 4);
    return f;
}
__device__ __forceinline__ unsigned short f2bf(float f) {
    unsigned int x;
    __builtin_memcpy(&x, &f, 4);
    unsigned int r = (x + 0x7fffu + ((x >> 16) & 1u)) >> 16;  // RNE
    return (unsigned short)r;
}
// split: hi = truncated bf16 (cheap), lo = RNE bf16 of residual.
__device__ __forceinline__ void split1(float v, unsigned short& hi, unsigned short& lo) {
    unsigned int x;
    __builtin_memcpy(&x, &v, 4);
    hi = (unsigned short)(x >> 16);
    lo = f2bf(v - bf2f(hi));
}
__device__ __forceinline__ float fast_sigmoid(float x) {
    return 1.0f / (1.0f + __expf(-x));
}
__device__ __forceinline__ float fast_tanh(float x) {
    float ax = fabsf(x);
    float e = __expf(2.0f * ax);
    float t = 1.0f - 2.0f / (e + 1.0f);
    return copysignf(t, x);
}

// 16B async global->LDS
__device__ __forceinline__ void gload_lds16(const void* g, void* lds) {
    __builtin_amdgcn_global_load_lds(
        (const __attribute__((address_space(1))) unsigned int*)g,
        (__attribute__((address_space(3))) unsigned int*)lds, 16, 0, 0);
}

// ---------- fused weight prep ----------
// [0,65536) Wih | [65536,81920) W1^T | [81920,98304) W2^T | [98304,114688) W3 | [114688,115200) bsum
__global__ void prep_weights_kernel(const float* __restrict__ Wih,
                                    const float* __restrict__ W1,
                                    const float* __restrict__ W2,
                                    const float* __restrict__ W3,
                                    const float* __restrict__ bih,
                                    const float* __restrict__ bhh,
                                    unsigned short* __restrict__ Wihh, unsigned short* __restrict__ Wihl,
                                    unsigned short* __restrict__ W1h,  unsigned short* __restrict__ W1l,
                                    unsigned short* __restrict__ W2h,  unsigned short* __restrict__ W2l,
                                    unsigned short* __restrict__ W3h,  unsigned short* __restrict__ W3l,
                                    float* __restrict__ bsum) {
    int i = blockIdx.x * 256 + threadIdx.x;
    unsigned short h, l;
    if (i < 65536) {
        split1(Wih[i], h, l);
        Wihh[i] = h; Wihl[i] = l;
    } else if (i < 81920) {
        int t = i - 65536, r = t >> 7, c = t & 127;
        split1(W1[r * HDIM + c], h, l);
        W1h[c * HDIM + r] = h; W1l[c * HDIM + r] = l;
    } else if (i < 98304) {
        int t = i - 81920, r = t >> 7, c = t & 127;
        split1(W2[r * HDIM + c], h, l);
        W2h[c * HDIM + r] = h; W2l[c * HDIM + r] = l;
    } else if (i < 114688) {
        int t = i - 98304;
        split1(W3[t], h, l);
        W3h[t] = h; W3l[t] = l;
    } else if (i < 115200) {
        int t = i - 114688;
        bsum[t] = bih[t] + bhh[t];
    }
}

// ================= bucketed CSR build =================
__global__ __launch_bounds__(256)
void bucket_hist_kernel(const int* __restrict__ ei, int* __restrict__ bcnt,
                        long E, int K) {
    __shared__ int h[BKMAX];
    const int tid = threadIdx.x;
    for (int i = tid; i < K; i += 256) h[i] = 0;
    __syncthreads();
    const long base = (long)blockIdx.x * CHUNK;
#pragma unroll
    for (int j = 0; j < CHUNK / 256; ++j) {
        long e = base + j * 256 + tid;
        if (e < E) atomicAdd(&h[((unsigned)ei[E + e]) >> 8], 1);
    }
    __syncthreads();
    for (int i = tid; i < K; i += 256) {
        int c = h[i];
        if (c) atomicAdd(&bcnt[i], c);
    }
}

__global__ __launch_bounds__(1024)
void scan_buckets_kernel(const int* __restrict__ bcnt, int* __restrict__ gbase,
                         int* __restrict__ gcur, int* __restrict__ offs,
                         int K, int N, int Etot) {
    __shared__ int buf[1024];
    const int t = threadIdx.x;
    const int v = (t < K) ? bcnt[t] : 0;
    buf[t] = v;
    __syncthreads();
    for (int off = 1; off < 1024; off <<= 1) {
        int x = buf[t];
        int y = (t >= off) ? buf[t - off] : 0;
        __syncthreads();
        buf[t] = x + y;
        __syncthreads();
    }
    if (t < K) { gbase[t] = buf[t] - v; gcur[t] = buf[t] - v; }
    if (t == 0) { gbase[K] = Etot; offs[N] = Etot; }
}

__global__ __launch_bounds__(256)
void pair_scatter_kernel(const int* __restrict__ ei, int* __restrict__ gcur,
                         unsigned int* __restrict__ pairs, long E, int K) {
    __shared__ int h[BKMAX];
    __shared__ int cur[BKMAX];
    const int tid = threadIdx.x;
    for (int i = tid; i < K; i += 256) h[i] = 0;
    __syncthreads();
    const long base = (long)blockIdx.x * CHUNK;
#pragma unroll
    for (int j = 0; j < CHUNK / 256; ++j) {
        long e = base + j * 256 + tid;
        if (e < E) atomicAdd(&h[((unsigned)ei[E + e]) >> 8], 1);
    }
    __syncthreads();
    for (int i = tid; i < K; i += 256) {
        int c = h[i];
        cur[i] = c ? atomicAdd(&gcur[i], c) : 0;
    }
    __syncthreads();
#pragma unroll
    for (int j = 0; j < CHUNK / 256; ++j) {
        long e = base + j * 256 + tid;
        if (e < E) {
            unsigned int s = (unsigned int)ei[e];
            unsigned int d = (unsigned int)ei[E + e];
            int b = d >> 8;
            int pos = atomicAdd(&cur[b], 1);
            pairs[pos] = s | ((d & (NPB - 1)) << 24);
        }
    }
}

__global__ __launch_bounds__(256)
void bucket_csr_kernel(const unsigned int* __restrict__ pairs, const int* __restrict__ gbase,
                       int* __restrict__ offs, float* __restrict__ dinv,
                       int* __restrict__ srclist, int N) {
    __shared__ int cnt[NPB];
    __shared__ int red[NPB];
    __shared__ int cur[NPB];
    __shared__ int stage[STAGE_CAP];
    const int tid = threadIdx.x;
    const int b = blockIdx.x;
    const int node0 = b << 8;
    const int nn = min(NPB, N - node0);
    const int ebeg = gbase[b];
    const int eend = gbase[b + 1];
    const int ne = eend - ebeg;

    cnt[tid] = 0;
    __syncthreads();
    for (int i = tid; i < ne; i += 256)
        atomicAdd(&cnt[pairs[ebeg + i] >> 24], 1);
    __syncthreads();
    const int myc = cnt[tid];
    red[tid] = myc;
    __syncthreads();
    for (int off = 1; off < NPB; off <<= 1) {
        int x = red[tid];
        int y = (tid >= off) ? red[tid - off] : 0;
        __syncthreads();
        red[tid] = x + y;
        __syncthreads();
    }
    const int loff = red[tid] - myc;   // exclusive
    if (tid < nn) {
        offs[node0 + tid] = ebeg + loff;
        dinv[node0 + tid] = rsqrtf((float)myc + 1.0f);   // +1 self-loop
    }
    cur[tid] = loff;
    __syncthreads();

    if (ne <= STAGE_CAP) {
        for (int i = tid; i < ne; i += 256) {
            unsigned int p = pairs[ebeg + i];
            int pos = atomicAdd(&cur[p >> 24], 1);
            stage[pos] = (int)(p & 0xFFFFFFu);
        }
        __syncthreads();
        for (int i = tid; i < ne; i += 256)
            srclist[ebeg + i] = stage[i];
    } else {
        for (int i = tid; i < ne; i += 256) {
            unsigned int p = pairs[ebeg + i];
            int pos = atomicAdd(&cur[p >> 24], 1);
            srclist[ebeg + pos] = (int)(p & 0xFFFFFFu);
        }
    }
}

// ---------- swizzled B staging via global_load_lds (256 threads) ----------
// [nrows x 64] short plane (global pitch 128) -> LDS pitch 64, 16B chunks XOR-swizzled.
__device__ __forceinline__ void stage_swz(const unsigned short* __restrict__ g,
                                          long rowBase, long maxRow, int kOff,
                                          unsigned short* lds, int nrows, int tid) {
    const int nchunks = nrows << 3;
    for (int L = tid; L < nchunks; L += 256) {
        int r = L >> 3, cS = L & 7;
        int cG = cS ^ (r & 7);
        long gr = rowBase + r;
        if (gr >= maxRow) gr = maxRow - 1;
        gload_lds16(g + gr * HDIM + kOff + cG * 8, lds + (long)L * 8);
    }
}
__device__ __forceinline__ int swz_off(int r, int c0) {
    return (r * 8 + (c0 ^ (r & 7))) * 8;
}

// ---------- split-bf16 GEMM, register-resident A ----------
// C[m,n] = sum_k A[m,k]*B[n,k], 64-row M tile, K=128. A planes read global->VGPR.
// mode 0: outb = bf16( C * rowScale[m] );  mode 1: outf = relu(C + bias[n])
__global__ __launch_bounds__(256, 4)
void gemm_split(const unsigned short* __restrict__ Ah, const unsigned short* __restrict__ Al,
                const unsigned short* __restrict__ Bh, const unsigned short* __restrict__ Bl,
                float* __restrict__ outf, unsigned short* __restrict__ outb, long M,
                const float* __restrict__ rowScale,
                const float* __restrict__ bias, int mode)
{
    __shared__ unsigned short sBh[128 * 64], sBl[128 * 64];
    const int tid = threadIdx.x;
    const long rowBase = (long)blockIdx.x * 64;

    const int wave = tid >> 6;
    const int lane = tid & 63;
    const int quad = lane >> 4;
    const int l16  = lane & 15;
    const int arow = wave * 16 + l16;
    long ag = rowBase + arow;
    if (ag >= M) ag = M - 1;

    // A fragments: [h][kk], hi+lo planes, 16B contiguous per position
    short8 rah[2][2], ral[2][2];
#pragma unroll
    for (int h = 0; h < 2; ++h)
#pragma unroll
        for (int kk = 0; kk < 2; ++kk) {
            const long o = ag * HDIM + h * 64 + kk * 32 + quad * 8;
            rah[h][kk] = *(const short8*)(Ah + o);
            ral[h][kk] = *(const short8*)(Al + o);
        }

    floatx4 acc[8];
#pragma unroll
    for (int i = 0; i < 8; ++i) acc[i] = (floatx4)0.0f;

    for (int h = 0; h < 2; ++h) {
        __syncthreads();
        stage_swz(Bh, 0, 128, h * 64, sBh, 128, tid);
        stage_swz(Bl, 0, 128, h * 64, sBl, 128, tid);
        __syncthreads();
#pragma unroll
        for (int kk = 0; kk < 2; ++kk) {
            const int c0 = kk * 4 + quad;
            short8 ah = rah[h][kk];
            short8 al = ral[h][kk];
#pragma unroll
            for (int ct = 0; ct < 8; ++ct) {
                const int bo = swz_off(ct * 16 + l16, c0);
                short8 bh = *(const short8*)(sBh + bo);
                short8 bl = *(const short8*)(sBl + bo);
                acc[ct] = __builtin_amdgcn_mfma_f32_16x16x32_bf16(ah, bh, acc[ct], 0, 0, 0);
                acc[ct] = __builtin_amdgcn_mfma_f32_16x16x32_bf16(ah, bl, acc[ct], 0, 0, 0);
                acc[ct] = __builtin_amdgcn_mfma_f32_16x16x32_bf16(al, bh, acc[ct], 0, 0, 0);
            }
        }
    }

#pragma unroll
    for (int ct = 0; ct < 8; ++ct) {
#pragma unroll
        for (int r = 0; r < 4; ++r) {
            long m = rowBase + wave * 16 + quad * 4 + r;
            if (m < M) {
                int n = ct * 16 + l16;
                float v = acc[ct][r];
                if (mode == 0) {
                    v *= rowScale[m];
                    outb[m * HDIM + n] = f2bf(v);
                } else {
                    v += bias[n];
                    v = fmaxf(v, 0.0f);
                    outf[m * HDIM + n] = v;
                }
            }
        }
    }
}

// ---------- LSTM: gates = z @ W_ih^T + bsum (f dead, h0=c0=0) ----------
// z read raw fp32 global->VGPR, split in-register (no split_plane pass, no A staging).
__global__ __launch_bounds__(256, 3)
void lstm_gemm_split(const float* __restrict__ Z,
                     const unsigned short* __restrict__ Wh, const unsigned short* __restrict__ Wl,
                     const float* __restrict__ bsum,
                     unsigned short* __restrict__ Hh, unsigned short* __restrict__ Hl, long M)
{
    __shared__ unsigned short sBh[128 * 64], sBl[128 * 64];
    const int tid = threadIdx.x;
    const long rowBase = (long)blockIdx.x * 64;

    const int wave = tid >> 6;
    const int lane = tid & 63;
    const int quad = lane >> 4;
    const int l16  = lane & 15;
    const int arow = wave * 16 + l16;
    long ag = rowBase + arow;
    if (ag >= M) ag = M - 1;

    // load fp32 z fragments and split to bf16 hi/lo in-register
    short8 rah[2][2], ral[2][2];
#pragma unroll
    for (int h = 0; h < 2; ++h)
#pragma unroll
        for (int kk = 0; kk < 2; ++kk) {
            const float* p = Z + ag * HDIM + h * 64 + kk * 32 + quad * 8;
            float4 f0 = *(const float4*)p;
            float4 f1 = *(const float4*)(p + 4);
            float f[8] = {f0.x, f0.y, f0.z, f0.w, f1.x, f1.y, f1.z, f1.w};
#pragma unroll
            for (int e = 0; e < 8; ++e) {
                unsigned short hi, lo;
                split1(f[e], hi, lo);
                rah[h][kk][e] = (short)hi;
                ral[h][kk][e] = (short)lo;
            }
        }

    floatx4 acc[3][8];
#pragma unroll
    for (int g = 0; g < 3; ++g)
#pragma unroll
        for (int i = 0; i < 8; ++i) acc[g][i] = (floatx4)0.0f;

    const int gateRow[3] = {0, 256, 384};   // i, g, o
    for (int h = 0; h < 2; ++h) {
        for (int g = 0; g < 3; ++g) {
            __syncthreads();
            stage_swz(Wh + (long)gateRow[g] * HDIM, 0, 1 << 30, h * 64, sBh, 128, tid);
            stage_swz(Wl + (long)gateRow[g] * HDIM, 0, 1 << 30, h * 64, sBl, 128, tid);
            __syncthreads();
#pragma unroll
            for (int kk = 0; kk < 2; ++kk) {
                const int c0 = kk * 4 + quad;
                short8 ah = rah[h][kk];
                short8 al = ral[h][kk];
#pragma unroll
                for (int ct = 0; ct < 8; ++ct) {
                    const int bo = swz_off(ct * 16 + l16, c0);
                    short8 bh = *(const short8*)(sBh + bo);
                    short8 bl = *(const short8*)(sBl + bo);
                    acc[g][ct] = __builtin_amdgcn_mfma_f32_16x16x32_bf16(ah, bh, acc[g][ct], 0, 0, 0);
                    acc[g][ct] = __builtin_amdgcn_mfma_f32_16x16x32_bf16(ah, bl, acc[g][ct], 0, 0, 0);
                    acc[g][ct] = __builtin_amdgcn_mfma_f32_16x16x32_bf16(al, bh, acc[g][ct], 0, 0, 0);
                }
            }
        }
    }

#pragma unroll
    for (int ct = 0; ct < 8; ++ct) {
#pragma unroll
        for (int r = 0; r < 4; ++r) {
            long m = rowBase + wave * 16 + quad * 4 + r;
            if (m < M) {
                int n = ct * 16 + l16;
                float iv = acc[0][ct][r] + bsum[n];
                float gv = acc[1][ct][r] + bsum[256 + n];
                float ov = acc[2][ct][r] + bsum[384 + n];
                float cv = fast_sigmoid(iv) * fast_tanh(gv);
                float hv = fast_sigmoid(ov) * fast_tanh(cv);
                unsigned short hh, hl;
                split1(hv, hh, hl);
                Hh[m * HDIM + n] = hh;
                Hl[m * HDIM + n] = hl;
            }
        }
    }
}

// ---------- pull aggregation over bf16 messages (unroll 8) ----------
__global__ __launch_bounds__(256, 4)
void aggregate_kernel(const unsigned short* __restrict__ t, const int* __restrict__ srclist,
                      const int* __restrict__ offs, const float* __restrict__ dinv,
                      const float* __restrict__ bias, int doRelu,
                      unsigned short* __restrict__ Xh, unsigned short* __restrict__ Xl, long N)
{
    long node = (long)blockIdx.x * 4 + (threadIdx.x >> 6);
    if (node >= N) return;
    const int lane = threadIdx.x & 63;
    const int c = lane * 2;
    const int beg = offs[node];
    const int end = offs[node + 1];
    float s0[8], s1[8];
#pragma unroll
    for (int q = 0; q < 8; ++q) { s0[q] = 0.0f; s1[q] = 0.0f; }
    int j = beg;
    for (; j + 8 <= end; j += 8) {
        int srcs[8];
#pragma unroll
        for (int q = 0; q < 8; ++q) srcs[q] = srclist[j + q];
        unsigned int p[8];
#pragma unroll
        for (int q = 0; q < 8; ++q) p[q] = *(const unsigned int*)(t + (long)srcs[q] * HDIM + c);
#pragma unroll
        for (int q = 0; q < 8; ++q) {
            s0[q] += bf2f((unsigned short)(p[q] & 0xffffu));
            s1[q] += bf2f((unsigned short)(p[q] >> 16));
        }
    }
    for (; j + 4 <= end; j += 4) {
        int srcs[4];
#pragma unroll
        for (int q = 0; q < 4; ++q) srcs[q] = srclist[j + q];
#pragma unroll
        for (int q = 0; q < 4; ++q) {
            unsigned int p = *(const unsigned int*)(t + (long)srcs[q] * HDIM + c);
            s0[q] += bf2f((unsigned short)(p & 0xffffu));
            s1[q] += bf2f((unsigned short)(p >> 16));
        }
    }
    for (; j < end; ++j) {
        unsigned int p = *(const unsigned int*)(t + (long)srclist[j] * HDIM + c);
        s0[0] += bf2f((unsigned short)(p & 0xffffu));
        s1[0] += bf2f((unsigned short)(p >> 16));
    }
    const unsigned int ps = *(const unsigned int*)(t + node * HDIM + c);
    s0[0] += bf2f((unsigned short)(ps & 0xffffu));    // self-loop
    s1[0] += bf2f((unsigned short)(ps >> 16));
    float a0 = ((s0[0] + s0[1]) + (s0[2] + s0[3])) + ((s0[4] + s0[5]) + (s0[6] + s0[7]));
    float a1 = ((s1[0] + s1[1]) + (s1[2] + s1[3])) + ((s1[4] + s1[5]) + (s1[6] + s1[7]));
    const float d = dinv[node];
    float v0 = d * a0 + bias[c];
    float v1 = d * a1 + bias[c + 1];
    if (doRelu) { v0 = fmaxf(v0, 0.0f); v1 = fmaxf(v1, 0.0f); }
    unsigned short h0, l0, h1, l1;
    split1(v0, h0, l0);
    split1(v1, h1, l1);
    *(unsigned int*)(Xh + node * HDIM + c) = (unsigned int)h0 | ((unsigned int)h1 << 16);
    *(unsigned int*)(Xl + node * HDIM + c) = (unsigned int)l0 | ((unsigned int)l1 << 16);
}

extern "C" void kernel_launch(void* const* d_in, const int* in_sizes, int n_in,
                              void* d_out, int out_size, void* d_ws, size_t ws_size,
                              hipStream_t stream)
{
    const float* z   = (const float*)d_in[0];
    const int*   ei  = (const int*)d_in[1];
    const float* Wih = (const float*)d_in[2];
    /* d_in[3] = W_hh: unused (h0 = 0) */
    const float* bih = (const float*)d_in[4];
    const float* bhh = (const float*)d_in[5];
    const float* W1  = (const float*)d_in[6];
    const float* b1  = (const float*)d_in[7];
    const float* W2  = (const float*)d_in[8];
    const float* b2  = (const float*)d_in[9];
    const float* W3  = (const float*)d_in[10];
    const float* b3  = (const float*)d_in[11];
    float* out = (float*)d_out;

    const long N = in_sizes[0] / HDIM;
    const long E = in_sizes[1] / 2;
    const int  K = (int)((N + NPB - 1) / NPB);

    char* ws = (char*)d_ws;
    size_t off = 0;
    auto alloc = [&](size_t bytes) {
        char* p = ws + off;
        off += (bytes + 255) & ~(size_t)255;
        return (void*)p;
    };
    int*   bcnt    = (int*)alloc(K * 4);
    int*   gbase   = (int*)alloc((K + 1) * 4);
    int*   gcur    = (int*)alloc(K * 4);
    int*   offs    = (int*)alloc((N + 1) * 4);
    float* dinv    = (float*)alloc(N * 4);
    unsigned int* pairs = (unsigned int*)alloc(E * 4);
    int*   srclist = (int*)alloc(E * 4);
    unsigned short* P1h = (unsigned short*)alloc(N * HDIM * 2);  // x1 planes
    unsigned short* P1l = (unsigned short*)alloc(N * HDIM * 2);
    unsigned short* P2h = (unsigned short*)alloc(N * HDIM * 2);  // h planes -> x2 planes
    unsigned short* P2l = (unsigned short*)alloc(N * HDIM * 2);
    unsigned short* Tb  = (unsigned short*)alloc(N * HDIM * 2);  // scaled messages (bf16)
    unsigned short* Wihh = (unsigned short*)alloc(512 * HDIM * 2);
    unsigned short* Wihl = (unsigned short*)alloc(512 * HDIM * 2);
    unsigned short* W1h  = (unsigned short*)alloc(HDIM * HDIM * 2);
    unsigned short* W1l  = (unsigned short*)alloc(HDIM * HDIM * 2);
    unsigned short* W2h  = (unsigned short*)alloc(HDIM * HDIM * 2);
    unsigned short* W2l  = (unsigned short*)alloc(HDIM * HDIM * 2);
    unsigned short* W3h  = (unsigned short*)alloc(HDIM * HDIM * 2);
    unsigned short* W3l  = (unsigned short*)alloc(HDIM * HDIM * 2);
    float* bsum = (float*)alloc(512 * 4);

    const int gblocks = (int)((N + 63) / 64);
    const int ablocks = (int)((N + 3) / 4);
    const int cblocks = (int)((E + CHUNK - 1) / CHUNK);

    // ---- bucketed CSR build ----
    hipMemsetAsync(bcnt, 0, K * 4, stream);
    bucket_hist_kernel<<<cblocks, 256, 0, stream>>>(ei, bcnt, E, K);
    scan_buckets_kernel<<<1, 1024, 0, stream>>>(bcnt, gbase, gcur, offs, K, (int)N, (int)E);
    pair_scatter_kernel<<<cblocks, 256, 0, stream>>>(ei, gcur, pairs, E, K);
    bucket_csr_kernel<<<K, 256, 0, stream>>>(pairs, gbase, offs, dinv, srclist, (int)N);

    // weight prep
    prep_weights_kernel<<<451, 256, 0, stream>>>(Wih, W1, W2, W3, bih, bhh,
                                                 Wihh, Wihl, W1h, W1l, W2h, W2l, W3h, W3l, bsum);

    // h = lstm(z)  (z read fp32 directly) -> P2 planes
    lstm_gemm_split<<<gblocks, 256, 0, stream>>>(z, Wihh, Wihl, bsum, P2h, P2l, N);

    // layer 1
    gemm_split<<<gblocks, 256, 0, stream>>>(P2h, P2l, W1h, W1l, nullptr, Tb, N, dinv, nullptr, 0);
    aggregate_kernel<<<ablocks, 256, 0, stream>>>(Tb, srclist, offs, dinv, b1, 1, P1h, P1l, N);

    // layer 2
    gemm_split<<<gblocks, 256, 0, stream>>>(P1h, P1l, W2h, W2l, nullptr, Tb, N, dinv, nullptr, 0);
    aggregate_kernel<<<ablocks, 256, 0, stream>>>(Tb, srclist, offs, dinv, b2, 0, P2h, P2l, N);

    // out = relu(x2 @ W3^T + b3)
    gemm_split<<<gblocks, 256, 0, stream>>>(P2h, P2l, W3h, W3l, out, nullptr, N, nullptr, b3, 1);
}